// Round 2
// baseline (277.163 us; speedup 1.0000x reference)
//
#include <hip/hip_runtime.h>
#include <cstdint>

// Fisher-Kolmogorov explicit Euler, B=2, 128^3, up to 30 masked micro-steps
// (delta_t_days = randint(0,4) -> d <= 3 -> steps <= 30).
// Round-11: 3 steps/launch (R10) RESTRUCTURED as z-marched plane pipeline.
//  R10 post-mortem: 78 KB LDS -> 2 blocks/CU (8 waves) made the kernel
//  latency-bound; fusion gained only 10 us. This version keeps the fusion
//  but shrinks LDS to 21.5 KB via 3-plane rings per step level:
//    ring1[3][8][128] (step-1 planes), ring2[3][6][128] (step-2 planes).
//  TY=4 -> plane tasks = 8 rows x 32 f4 = 256 = 1 task/thread: uniform
//  mapping, rolled-register z-column in phase A, no halo sub-loops.
//  __launch_bounds__(256,4): 4 blocks/CU = 16 waves/CU (R5 evidence: 16
//  waves ~2x over 8 on this stencil). dr re-read from L2 per step level
//  (mapping no longer aligns across phases); +8 B/cell L2 is cheap.
//  Schedule per z-iter i (z1 = z0-2+i, 8 iters):
//    A: s1[z1] -> ring1[i%3]            (needs src z1-1,z1,z1+1; rolled)
//    sync
//    B (i>=2): s2[z1-1] -> ring2[(i-2)%3] (reads ring1 slots i-2,i-1,i)
//    sync
//    C (i>=4): out[z1-2] -> global        (reads ring2 slots i-4,i-3,i-2)
//  Ring overwrite hazards are covered by the 2 syncs/iter (traced).

constexpr int NX = 128, NY = 128, NZ = 128;
constexpr int PLANE = NX * NY;            // 16384
constexpr int VOL   = NZ * PLANE;         // 2,097,152
constexpr int TOTAL = 2 * VOL;            // 4,194,304
constexpr float DT  = 0.1f;               // MICRO_DT
constexpr int MAX_TRIPLES = 10;           // 30 steps / 3

constexpr int TY = 4, TZ = 4;             // block interior tile (x full 128)
constexpr int BLOCKS = 2 * (NZ / TZ) * (NY / TY);  // 2*32*32 = 2048

__device__ __forceinline__ float4 ld4(const float* p) { return *(const float4*)p; }

__device__ __forceinline__ uint32_t f2bf(float f) {
    uint32_t u = __float_as_uint(f);
    u += 0x7fffu + ((u >> 16) & 1u);      // round-to-nearest-even
    return u >> 16;
}
__device__ __forceinline__ float bf_lo(uint32_t p) { return __uint_as_float(p << 16); }
__device__ __forceinline__ float bf_hi(uint32_t p) { return __uint_as_float(p & 0xffff0000u); }
__device__ __forceinline__ float clip01(float v) { return fminf(fmaxf(v, 0.0f), 1.0f); }

__device__ __forceinline__ float4 fkstep(float dt, float4 c, float xm, float xp,
                                         float4 ym, float4 yp,
                                         float4 zm, float4 zp,
                                         float4 Dv, float4 Rv) {
    float4 o;
    o.x = fmaf(dt, fmaf(Dv.x, (xm + c.y) + (ym.x + yp.x) + (zm.x + zp.x) - 6.0f * c.x,
                        Rv.x * c.x * (1.0f - c.x)), c.x);
    o.y = fmaf(dt, fmaf(Dv.y, (c.x + c.z) + (ym.y + yp.y) + (zm.y + zp.y) - 6.0f * c.y,
                        Rv.y * c.y * (1.0f - c.y)), c.y);
    o.z = fmaf(dt, fmaf(Dv.z, (c.y + c.w) + (ym.z + yp.z) + (zm.z + zp.z) - 6.0f * c.z,
                        Rv.z * c.z * (1.0f - c.z)), c.z);
    o.w = fmaf(dt, fmaf(Dv.w, (c.z + xp) + (ym.w + yp.w) + (zm.w + zp.w) - 6.0f * c.w,
                        Rv.w * c.w * (1.0f - c.w)), c.w);
    return o;
}

__device__ __forceinline__ float4 unpackD(uint4 p) {
    return make_float4(bf_lo(p.x), bf_lo(p.y), bf_lo(p.z), bf_lo(p.w));
}
__device__ __forceinline__ float4 unpackR(uint4 p) {
    return make_float4(bf_hi(p.x), bf_hi(p.y), bf_hi(p.z), bf_hi(p.w));
}

__global__ __launch_bounds__(256, 4)
void fk_triple(const float* __restrict__ src, float* __restrict__ dst0,
               float* __restrict__ out, const float* __restrict__ u0,
               const float* __restrict__ Dm, const float* __restrict__ Rm,
               uint32_t* __restrict__ dr, const int* __restrict__ dtd, int p)
{
    const int b  = blockIdx.x >> 10;                 // batch item (block-uniform)
    int d = dtd[b]; d = d < 0 ? 0 : (d > 3 ? 3 : d); // randint(0,4) is excl-upper
    const int steps = d * 10;
    const int g0 = 3 * p;                            // first global step of launch

    const int zb = (blockIdx.x >> 5) & 31;
    const int yt = blockIdx.x & 31;
    const int z0 = zb * TZ, y0 = yt * TY;
    const int tid = threadIdx.x;
    const int cxq = tid & 31;                        // float4 lane within row
    const int ry  = tid >> 5;                        // 0..7 (plane row)
    const int baseb = b << 21;
    const float4 zero = make_float4(0.f, 0.f, 0.f, 0.f);

    if (g0 >= steps) {
        // d==0 items never get a step write: emit clip(u0) once, in launch 0.
        if (steps == 0 && p == 0) {
            #pragma unroll
            for (int kk = 0; kk < 2; ++kk) {
                const int t  = tid + kk * 256;
                const int zk = t >> 7;               // 0..3
                const int yy = (t >> 5) & 3;         // 0..3
                const int cq = t & 31;
                const int idx = baseb + (z0 + zk) * PLANE + (y0 + yy) * NX + (cq << 2);
                const float4 v = ld4(u0 + idx);
                float4 o;
                o.x = clip01(v.x); o.y = clip01(v.y);
                o.z = clip01(v.z); o.w = clip01(v.w);
                *(float4*)(out + idx) = o;
            }
        }
        return;                                      // block-uniform exit
    }
    const bool first = (p == 0);
    const bool last  = (steps - g0 <= 3);
    float* __restrict__ dst = last ? out : dst0;
    const float m1 = (g0 + 1 < steps) ? DT : 0.0f;   // sub-step masks (g0 active)
    const float m2 = (g0 + 2 < steps) ? DT : 0.0f;   // fmaf(0,du,u)==u exactly

    __shared__ float r1[3][8][NX];                   // 12 KiB: step-1 plane ring
    __shared__ float r2[3][6][NX];                   //  9 KiB: step-2 plane ring

    // ---- Phase A setup: thread owns column (yA, cxq); rolled z registers ----
    const int  yA = y0 - 2 + ry;
    const bool vy = (unsigned)yA < (unsigned)NY;
    const int  colA = baseb + yA * NX + (cxq << 2);
    const bool hl = (cxq > 0), hr = (cxq < 31);

    float4 um = zero, uc = zero;
    if (vy) {
        if (z0 - 3 >= 0) um = ld4(src + colA + (z0 - 3) * PLANE);
        if (z0 - 2 >= 0) uc = ld4(src + colA + (z0 - 2) * PLANE);
    }

    #pragma unroll
    for (int i = 0; i < 8; ++i) {
        const int z1 = z0 - 2 + i;

        // ---- A: step-1 plane z1 -> ring1[i%3] (zeros when out of domain) ----
        float4 un = zero;
        if (vy && (unsigned)(z1 + 1) < (unsigned)NZ)
            un = ld4(src + colA + (z1 + 1) * PLANE);
        float4 o1 = zero;
        if (vy && (unsigned)z1 < (unsigned)NZ) {
            const int idx = colA + z1 * PLANE;
            const float4 ym4 = (yA > 0)      ? ld4(src + idx - NX) : zero;
            const float4 yp4 = (yA < NY - 1) ? ld4(src + idx + NX) : zero;
            const float xm = hl ? src[idx - 1] : 0.0f;
            const float xp = hr ? src[idx + 4] : 0.0f;
            float4 Dv, Rv;
            if (first) {
                Dv = ld4(Dm + idx);
                Rv = ld4(Rm + idx);
                // publish packed dr exactly once per cell across the grid:
                // interior rows (ry 2..5) and interior z (i 2..5) only.
                if (ry >= 2 && ry < 6 && i >= 2 && i < 6) {
                    uint4 pk;
                    pk.x = f2bf(Dv.x) | (f2bf(Rv.x) << 16);
                    pk.y = f2bf(Dv.y) | (f2bf(Rv.y) << 16);
                    pk.z = f2bf(Dv.z) | (f2bf(Rv.z) << 16);
                    pk.w = f2bf(Dv.w) | (f2bf(Rv.w) << 16);
                    *(uint4*)(dr + idx) = pk;
                }
            } else {
                const uint4 pk = *(const uint4*)(dr + idx);
                Dv = unpackD(pk);
                Rv = unpackR(pk);
            }
            o1 = fkstep(DT, uc, xm, xp, ym4, yp4, um, un, Dv, Rv);
        }
        *(float4*)&r1[i % 3][ry][cxq << 2] = o1;
        um = uc; uc = un;
        __syncthreads();

        // ---- B: step-2 plane z2 = z1-1 -> ring2[(i-2)%3] ----
        if (i >= 2) {
            const int z2 = z1 - 1;
            if (ry < 6) {
                float4 o2 = zero;
                const int yB = y0 - 1 + ry;
                if ((unsigned)z2 < (unsigned)NZ && (unsigned)yB < (unsigned)NY) {
                    const int sm = (i - 2) % 3, sc = (i - 1) % 3, sp = i % 3;
                    const float* rowc = &r1[sc][ry + 1][0];
                    const float4 cc  = *(const float4*)&rowc[cxq << 2];
                    const float xm = hl ? rowc[(cxq << 2) - 1] : 0.0f;
                    const float xp = hr ? rowc[(cxq << 2) + 4] : 0.0f;
                    const float4 ym4 = *(const float4*)&r1[sc][ry][cxq << 2];
                    const float4 yp4 = *(const float4*)&r1[sc][ry + 2][cxq << 2];
                    const float4 zm4 = *(const float4*)&r1[sm][ry + 1][cxq << 2];
                    const float4 zp4 = *(const float4*)&r1[sp][ry + 1][cxq << 2];
                    const int idx = baseb + z2 * PLANE + yB * NX + (cxq << 2);
                    float4 Dv, Rv;
                    if (first) {
                        Dv = ld4(Dm + idx);
                        Rv = ld4(Rm + idx);
                    } else {
                        const uint4 pk = *(const uint4*)(dr + idx);
                        Dv = unpackD(pk);
                        Rv = unpackR(pk);
                    }
                    o2 = fkstep(m1, cc, xm, xp, ym4, yp4, zm4, zp4, Dv, Rv);
                }
                *(float4*)&r2[(i - 2) % 3][ry][cxq << 2] = o2;
            }
        }
        __syncthreads();

        // ---- C: step-3 plane zo = z1-2 -> global (always in-domain) ----
        if (i >= 4 && ry < 4) {
            const int zo = z0 - 4 + i;
            const int yC = y0 + ry;
            const int qm = (i - 4) % 3, qc = (i - 3) % 3, qp = (i - 2) % 3;
            const float* rowc = &r2[qc][ry + 1][0];
            const float4 cc  = *(const float4*)&rowc[cxq << 2];
            const float xm = hl ? rowc[(cxq << 2) - 1] : 0.0f;
            const float xp = hr ? rowc[(cxq << 2) + 4] : 0.0f;
            const float4 ym4 = *(const float4*)&r2[qc][ry][cxq << 2];
            const float4 yp4 = *(const float4*)&r2[qc][ry + 2][cxq << 2];
            const float4 zm4 = *(const float4*)&r2[qm][ry + 1][cxq << 2];
            const float4 zp4 = *(const float4*)&r2[qp][ry + 1][cxq << 2];
            const int idx = baseb + zo * PLANE + yC * NX + (cxq << 2);
            float4 Dv, Rv;
            if (first) {
                Dv = ld4(Dm + idx);
                Rv = ld4(Rm + idx);
            } else {
                const uint4 pk = *(const uint4*)(dr + idx);
                Dv = unpackD(pk);
                Rv = unpackR(pk);
            }
            float4 o3 = fkstep(m2, cc, xm, xp, ym4, yp4, zm4, zp4, Dv, Rv);
            if (last) {
                o3.x = clip01(o3.x); o3.y = clip01(o3.y);
                o3.z = clip01(o3.z); o3.w = clip01(o3.w);
            }
            *(float4*)(dst + idx) = o3;
        }
    }
}

extern "C" void kernel_launch(void* const* d_in, const int* in_sizes, int n_in,
                              void* d_out, int out_size, void* d_ws, size_t ws_size,
                              hipStream_t stream) {
    const float* u0  = (const float*)d_in[0];
    const float* Dm  = (const float*)d_in[1];
    const float* Rm  = (const float*)d_in[2];
    const int*   dtd = (const int*)d_in[3];
    float* out = (float*)d_out;
    float* ws  = (float*)d_ws;
    // ws layout: [0,16M) buf0, [16M,32M) buf1, [32M,48M) packed DR (ws=256MB).
    float* buf[2] = { ws, ws + TOTAL };
    uint32_t* dr = (uint32_t*)(ws + 2 * TOTAL);

    // Launch p advances steps 3p..3p+2 (inactive sub-steps masked to identity).
    // src: u0 for p=0 else buf[(p-1)&1]; normal dst alternates buf[p&1]; an
    // item's LAST launch redirects to `out` (clipped) on-device. d==0 items
    // emit clip(u0) during launch 0.
    for (int p = 0; p < MAX_TRIPLES; ++p) {
        const float* src = (p == 0) ? u0 : buf[(p - 1) & 1];
        fk_triple<<<BLOCKS, 256, 0, stream>>>(src, buf[p & 1], out, u0,
                                              Dm, Rm, dr, dtd, p);
    }
}

// Round 3
// 234.527 us; speedup vs baseline: 1.1818x; 1.1818x over previous
//
#include <hip/hip_runtime.h>
#include <cstdint>

// Fisher-Kolmogorov explicit Euler, B=2, 128^3, up to 30 masked micro-steps
// (delta_t_days = randint(0,4) -> d <= 3 -> steps <= 30).
// Round-12: R10's 3-step blocked structure + s2-into-s1 LDS aliasing.
//  R11 post-mortem: plane-marched rings (16 barriers/launch, 4x redundancy)
//  regressed to 277us -> barrier count is a first-class cost here.
//  R10 post-mortem: fusion works but 78 KB LDS -> 2 blocks/CU (8 waves)
//  left the kernel latency-bound.
//  This round: keep R10's tile (TY=8, TZ=4), launch count (10), and traffic,
//  but stage phase-2 results in REGISTERS (~30 VGPR) and write them into
//  s1's dead storage after a barrier. LDS 78 -> 48 KB => 3 blocks/CU
//  (12 waves/CU). Barriers 2 -> 3 (not 16). launch_bounds(256,3) caps
//  VGPR at 168 to hold the occupancy.

constexpr int NX = 128, NY = 128, NZ = 128;
constexpr int PLANE = NX * NY;            // 16384
constexpr int VOL   = NZ * PLANE;         // 2,097,152
constexpr int TOTAL = 2 * VOL;            // 4,194,304
constexpr float DT  = 0.1f;               // MICRO_DT
constexpr int MAX_TRIPLES = 10;           // 30 steps / 3

constexpr int TY = 8, TZ = 4;             // block interior tile (x full 128)
constexpr int S1Z = TZ + 4, S1Y = TY + 4; // step-1 region: 8 z x 12 y (48 KB)
constexpr int S2Z = TZ + 2, S2Y = TY + 2; // step-2 region: 6 z x 10 y (30 KB, aliased)
constexpr int BLOCKS = 2 * (NZ / TZ) * (NY / TY);  // 2*32*16 = 1024

__device__ __forceinline__ float4 ld4(const float* p) { return *(const float4*)p; }

__device__ __forceinline__ uint32_t f2bf(float f) {
    uint32_t u = __float_as_uint(f);
    u += 0x7fffu + ((u >> 16) & 1u);      // round-to-nearest-even
    return u >> 16;
}
__device__ __forceinline__ float bf_lo(uint32_t p) { return __uint_as_float(p << 16); }
__device__ __forceinline__ float bf_hi(uint32_t p) { return __uint_as_float(p & 0xffff0000u); }
__device__ __forceinline__ float clip01(float v) { return fminf(fmaxf(v, 0.0f), 1.0f); }

__device__ __forceinline__ float4 fkstep(float dt, float4 c, float xm, float xp,
                                         float4 ym, float4 yp,
                                         float4 zm, float4 zp,
                                         float4 Dv, float4 Rv) {
    float4 o;
    o.x = fmaf(dt, fmaf(Dv.x, (xm + c.y) + (ym.x + yp.x) + (zm.x + zp.x) - 6.0f * c.x,
                        Rv.x * c.x * (1.0f - c.x)), c.x);
    o.y = fmaf(dt, fmaf(Dv.y, (c.x + c.z) + (ym.y + yp.y) + (zm.y + zp.y) - 6.0f * c.y,
                        Rv.y * c.y * (1.0f - c.y)), c.y);
    o.z = fmaf(dt, fmaf(Dv.z, (c.y + c.w) + (ym.z + yp.z) + (zm.z + zp.z) - 6.0f * c.z,
                        Rv.z * c.z * (1.0f - c.z)), c.z);
    o.w = fmaf(dt, fmaf(Dv.w, (c.z + xp) + (ym.w + yp.w) + (zm.w + zp.w) - 6.0f * c.w,
                        Rv.w * c.w * (1.0f - c.w)), c.w);
    return o;
}

__device__ __forceinline__ float4 unpackD(uint4 p) {
    return make_float4(bf_lo(p.x), bf_lo(p.y), bf_lo(p.z), bf_lo(p.w));
}
__device__ __forceinline__ float4 unpackR(uint4 p) {
    return make_float4(bf_hi(p.x), bf_hi(p.y), bf_hi(p.z), bf_hi(p.w));
}

__global__ __launch_bounds__(256, 3)
void fk_triple(const float* __restrict__ src, float* __restrict__ dst0,
               float* __restrict__ out, const float* __restrict__ u0,
               const float* __restrict__ Dm, const float* __restrict__ Rm,
               uint32_t* __restrict__ dr, const int* __restrict__ dtd, int p)
{
    const int b  = blockIdx.x >> 9;                  // batch item (block-uniform)
    int d = dtd[b]; d = d < 0 ? 0 : (d > 3 ? 3 : d); // randint(0,4) is excl-upper
    const int steps = d * 10;
    const int g0 = 3 * p;                            // first global step of launch

    const int zb = (blockIdx.x >> 4) & 31;
    const int yt = blockIdx.x & 15;
    const int z0 = zb * TZ, y0 = yt * TY;
    const int tid = threadIdx.x;
    const int xq  = tid & 31;                        // float4 lane within row
    const int yi  = tid >> 5;                        // 0..7
    const int baseb = b << 21;
    const float4 zero = make_float4(0.f, 0.f, 0.f, 0.f);

    if (g0 >= steps) {
        // d==0 items never get a step write: emit clip(u0) once, in launch 0.
        if (steps == 0 && p == 0) {
            #pragma unroll
            for (int k = 0; k < TZ; ++k) {
                const int idx = baseb + (z0 + k) * PLANE + (y0 + yi) * NX + (xq << 2);
                const float4 v = ld4(u0 + idx);
                float4 o;
                o.x = clip01(v.x); o.y = clip01(v.y);
                o.z = clip01(v.z); o.w = clip01(v.w);
                *(float4*)(out + idx) = o;
            }
        }
        return;                                      // block-uniform exit
    }
    const bool first = (p == 0);
    const bool last  = (steps - g0 <= 3);
    float* __restrict__ dst = last ? out : dst0;
    const float m1 = (g0 + 1 < steps) ? DT : 0.0f;   // sub-step masks (g0 active)
    const float m2 = (g0 + 2 < steps) ? DT : 0.0f;   // fmaf(0,du,u)==u exactly

    __shared__ float s1[S1Z * S1Y * NX];             // 48 KiB; s2 aliases this
    float* const s2b = s1;                           // s2 layout: [S2Z][S2Y][NX]

    uint4 pr[TZ];                                    // packed (D,rho) bf16, interior

    // ---- Phase 1 pass 0: step-1 on interior-y columns of s1, z-rolled over
    // all 8 s1 planes (z0-2 .. z0+5). Captures/publishes interior dr. ----
    {
        const int y = y0 + yi;                       // in-domain by construction
        const int colbase = baseb + y * NX + (xq << 2);
        const bool has_ym = (y > 0), has_yp = (y < NY - 1);
        const bool has_l = (xq > 0), has_r = (xq < 31);
        const int zlo = z0 - 2;

        float4 um = ((unsigned)(zlo - 1) < (unsigned)NZ) ? ld4(src + colbase + (zlo - 1) * PLANE) : zero;
        float4 uc = ((unsigned)zlo < (unsigned)NZ) ? ld4(src + colbase + zlo * PLANE) : zero;
        #pragma unroll
        for (int rz = 0; rz < S1Z; ++rz) {
            const int z = zlo + rz;
            const int idx = colbase + z * PLANE;
            const float4 un = ((unsigned)(z + 1) < (unsigned)NZ) ? ld4(src + idx + PLANE) : zero;
            float4 o = zero;
            if ((unsigned)z < (unsigned)NZ) {
                const float4 ym4 = has_ym ? ld4(src + idx - NX) : zero;
                const float4 yp4 = has_yp ? ld4(src + idx + NX) : zero;
                const float xm = has_l ? src[idx - 1] : 0.0f;
                const float xp = has_r ? src[idx + 4] : 0.0f;
                float4 Dv, Rv;
                if (first) {
                    Dv = ld4(Dm + idx);
                    Rv = ld4(Rm + idx);
                    if (rz >= 2 && rz < 2 + TZ) {    // interior z: publish + keep
                        uint4 pk;
                        pk.x = f2bf(Dv.x) | (f2bf(Rv.x) << 16);
                        pk.y = f2bf(Dv.y) | (f2bf(Rv.y) << 16);
                        pk.z = f2bf(Dv.z) | (f2bf(Rv.z) << 16);
                        pk.w = f2bf(Dv.w) | (f2bf(Rv.w) << 16);
                        *(uint4*)(dr + idx) = pk;
                        pr[rz - 2] = pk;
                    }
                } else {
                    const uint4 pk = *(const uint4*)(dr + idx);
                    Dv = unpackD(pk);
                    Rv = unpackR(pk);
                    if (rz >= 2 && rz < 2 + TZ) pr[rz - 2] = pk;
                }
                o = fkstep(DT, uc, xm, xp, ym4, yp4, um, un, Dv, Rv);
            }
            *(float4*)&s1[(rz * S1Y + (yi + 2)) * NX + (xq << 2)] = o;
            um = uc; uc = un;
        }
    }

    // ---- Phase 1 pass 1: step-1 on the 4 y-halo rows x 8 planes (32 row-
    // tasks, flat over all threads, 4 iterations). ----
    for (int i = tid; i < 32 * 32; i += 256) {
        const int cxq = i & 31;
        const int r   = i >> 5;                      // 0..31
        const int rr  = r >> 3;                      // 0..3
        const int rz  = r & 7;
        const int ry  = (rr < 2) ? rr : rr + 8;      // 0,1,10,11
        const int y = y0 - 2 + ry;
        const int z = z0 - 2 + rz;
        float4 o = zero;                             // out-of-domain -> 0
        if ((unsigned)y < (unsigned)NY && (unsigned)z < (unsigned)NZ) {
            const int idx = baseb + z * PLANE + y * NX + (cxq << 2);
            const float4 c  = ld4(src + idx);
            const float xm  = (cxq > 0)  ? src[idx - 1] : 0.0f;
            const float xp  = (cxq < 31) ? src[idx + 4] : 0.0f;
            const float4 ym4 = (y > 0)      ? ld4(src + idx - NX)    : zero;
            const float4 yp4 = (y < NY - 1) ? ld4(src + idx + NX)    : zero;
            const float4 zm4 = (z > 0)      ? ld4(src + idx - PLANE) : zero;
            const float4 zp4 = (z < NZ - 1) ? ld4(src + idx + PLANE) : zero;
            float4 Dv, Rv;
            if (first) {
                Dv = ld4(Dm + idx);
                Rv = ld4(Rm + idx);
            } else {
                const uint4 pk = *(const uint4*)(dr + idx);
                Dv = unpackD(pk);
                Rv = unpackR(pk);
            }
            o = fkstep(DT, c, xm, xp, ym4, yp4, zm4, zp4, Dv, Rv);
        }
        *(float4*)&s1[(rz * S1Y + ry) * NX + (cxq << 2)] = o;
    }
    __syncthreads();                                 // barrier 1: s1 complete

    // ---- Phase 2 (REGISTER-STAGED): step-2 values computed from s1 into
    // registers; no LDS writes until s1 reads are globally done. ----
    float4 s2i[S2Z];                                 // interior rows, ry2 = yi+1

    {
        const int ry1 = yi + 2;                      // this cell's s1 row
        float4 zmv = *(const float4*)&s1[(0 * S1Y + ry1) * NX + (xq << 2)];
        float4 cv  = *(const float4*)&s1[(1 * S1Y + ry1) * NX + (xq << 2)];
        #pragma unroll
        for (int rz2 = 0; rz2 < S2Z; ++rz2) {
            const int rz1 = rz2 + 1;
            const float4 zpv = *(const float4*)&s1[((rz1 + 1) * S1Y + ry1) * NX + (xq << 2)];
            const int z = z0 - 1 + rz2;
            float4 o = zero;
            if ((unsigned)z < (unsigned)NZ) {
                const float* rowc = &s1[(rz1 * S1Y + ry1) * NX];
                const float xm = (xq > 0)  ? rowc[(xq << 2) - 1] : 0.0f;
                const float xp = (xq < 31) ? rowc[(xq << 2) + 4] : 0.0f;
                const float4 ym4 = *(const float4*)&s1[(rz1 * S1Y + ry1 - 1) * NX + (xq << 2)];
                const float4 yp4 = *(const float4*)&s1[(rz1 * S1Y + ry1 + 1) * NX + (xq << 2)];
                float4 Dv, Rv;
                if (rz2 >= 1 && rz2 < 1 + TZ) {      // interior z: from registers
                    Dv = unpackD(pr[rz2 - 1]);
                    Rv = unpackR(pr[rz2 - 1]);
                } else {                             // z halo planes
                    const int idx = baseb + z * PLANE + (y0 + yi) * NX + (xq << 2);
                    if (first) {
                        Dv = ld4(Dm + idx);
                        Rv = ld4(Rm + idx);
                    } else {
                        const uint4 pk = *(const uint4*)(dr + idx);
                        Dv = unpackD(pk);
                        Rv = unpackR(pk);
                    }
                }
                o = fkstep(m1, cv, xm, xp, ym4, yp4, zmv, zpv, Dv, Rv);
            }
            s2i[rz2] = o;
            zmv = cv; cv = zpv;
        }
    }

    // y-halo rows of s2: 12 row-tasks x 32 f4 = 384 tasks; thread handles
    // task tid and (tid+256 if < 384). Results staged in registers.
    float4 s2h0 = zero, s2h1 = zero;
    #pragma unroll
    for (int kk = 0; kk < 2; ++kk) {
        const int i = tid + kk * 256;
        if (i < 12 * 32) {
            const int cxq = i & 31;
            const int r   = i >> 5;                  // 0..11
            const int ry2 = (r < 6) ? 0 : 9;
            const int rz2 = (r < 6) ? r : r - 6;
            const int y = y0 - 1 + ry2;
            const int z = z0 - 1 + rz2;
            float4 o = zero;
            if ((unsigned)y < (unsigned)NY && (unsigned)z < (unsigned)NZ) {
                const int rz1 = rz2 + 1, ry1 = ry2 + 1;
                const float* rowc = &s1[(rz1 * S1Y + ry1) * NX];
                const float4 cv = *(const float4*)&rowc[cxq << 2];
                const float xm = (cxq > 0)  ? rowc[(cxq << 2) - 1] : 0.0f;
                const float xp = (cxq < 31) ? rowc[(cxq << 2) + 4] : 0.0f;
                const float4 ym4 = *(const float4*)&s1[(rz1 * S1Y + ry1 - 1) * NX + (cxq << 2)];
                const float4 yp4 = *(const float4*)&s1[(rz1 * S1Y + ry1 + 1) * NX + (cxq << 2)];
                const float4 zm4 = *(const float4*)&s1[((rz1 - 1) * S1Y + ry1) * NX + (cxq << 2)];
                const float4 zp4 = *(const float4*)&s1[((rz1 + 1) * S1Y + ry1) * NX + (cxq << 2)];
                float4 Dv, Rv;
                const int idx = baseb + z * PLANE + y * NX + (cxq << 2);
                if (first) {
                    Dv = ld4(Dm + idx);
                    Rv = ld4(Rm + idx);
                } else {
                    const uint4 pk = *(const uint4*)(dr + idx);
                    Dv = unpackD(pk);
                    Rv = unpackR(pk);
                }
                o = fkstep(m1, cv, xm, xp, ym4, yp4, zm4, zp4, Dv, Rv);
            }
            if (kk == 0) s2h0 = o; else s2h1 = o;
        }
    }
    __syncthreads();                                 // barrier 2: s1 reads done

    // ---- Publish staged s2 into s1's storage (s2 layout) ----
    {
        const int ry2 = yi + 1;
        #pragma unroll
        for (int rz2 = 0; rz2 < S2Z; ++rz2)
            *(float4*)&s2b[(rz2 * S2Y + ry2) * NX + (xq << 2)] = s2i[rz2];
        #pragma unroll
        for (int kk = 0; kk < 2; ++kk) {
            const int i = tid + kk * 256;
            if (i < 12 * 32) {
                const int cxq = i & 31;
                const int r   = i >> 5;
                const int ry2h = (r < 6) ? 0 : 9;
                const int rz2h = (r < 6) ? r : r - 6;
                *(float4*)&s2b[(rz2h * S2Y + ry2h) * NX + (cxq << 2)] = (kk == 0) ? s2h0 : s2h1;
            }
        }
    }
    __syncthreads();                                 // barrier 3: s2 complete

    // ---- Phase 3: step-3 on the interior from s2 (aliased LDS); dr from
    // registers; z-rolled s2 planes; clip + redirect to `out` on last. ----
    {
        const int ry2 = yi + 1;
        const int y   = y0 + yi;
        float4 zmv = *(const float4*)&s2b[(0 * S2Y + ry2) * NX + (xq << 2)];
        float4 cv  = *(const float4*)&s2b[(1 * S2Y + ry2) * NX + (xq << 2)];
        #pragma unroll
        for (int k = 0; k < TZ; ++k) {
            const int rz2 = k + 1;
            const float4 zpv = *(const float4*)&s2b[((rz2 + 1) * S2Y + ry2) * NX + (xq << 2)];
            const float* rowc = &s2b[(rz2 * S2Y + ry2) * NX];
            const float xm = (xq > 0)  ? rowc[(xq << 2) - 1] : 0.0f;
            const float xp = (xq < 31) ? rowc[(xq << 2) + 4] : 0.0f;
            const float4 ym4 = *(const float4*)&s2b[(rz2 * S2Y + ry2 - 1) * NX + (xq << 2)];
            const float4 yp4 = *(const float4*)&s2b[(rz2 * S2Y + ry2 + 1) * NX + (xq << 2)];

            float4 o = fkstep(m2, cv, xm, xp, ym4, yp4, zmv, zpv,
                              unpackD(pr[k]), unpackR(pr[k]));
            if (last) {
                o.x = clip01(o.x); o.y = clip01(o.y);
                o.z = clip01(o.z); o.w = clip01(o.w);
            }
            const int idx = baseb + (z0 + k) * PLANE + y * NX + (xq << 2);
            *(float4*)(dst + idx) = o;
            zmv = cv; cv = zpv;
        }
    }
}

extern "C" void kernel_launch(void* const* d_in, const int* in_sizes, int n_in,
                              void* d_out, int out_size, void* d_ws, size_t ws_size,
                              hipStream_t stream) {
    const float* u0  = (const float*)d_in[0];
    const float* Dm  = (const float*)d_in[1];
    const float* Rm  = (const float*)d_in[2];
    const int*   dtd = (const int*)d_in[3];
    float* out = (float*)d_out;
    float* ws  = (float*)d_ws;
    // ws layout: [0,16M) buf0, [16M,32M) buf1, [32M,48M) packed DR (ws=256MB).
    float* buf[2] = { ws, ws + TOTAL };
    uint32_t* dr = (uint32_t*)(ws + 2 * TOTAL);

    // Launch p advances steps 3p..3p+2 (inactive sub-steps masked to identity).
    // src: u0 for p=0 else buf[(p-1)&1]; normal dst alternates buf[p&1]; an
    // item's LAST launch redirects to `out` (clipped) on-device. d==0 items
    // emit clip(u0) during launch 0.
    for (int p = 0; p < MAX_TRIPLES; ++p) {
        const float* src = (p == 0) ? u0 : buf[(p - 1) & 1];
        fk_triple<<<BLOCKS, 256, 0, stream>>>(src, buf[p & 1], out, u0,
                                              Dm, Rm, dr, dtd, p);
    }
}